// Round 1
// baseline (642.580 us; speedup 1.0000x reference)
//
#include <hip/hip_runtime.h>

using short8  = __attribute__((ext_vector_type(8))) short;
using short4v = __attribute__((ext_vector_type(4))) short;
using float4v = __attribute__((ext_vector_type(4))) float;

#define IMG  224
#define CDIM 96
#define NTOK 49
#define STQ  104   // q_s/k_s row stride (tokens x channels), 208B = 13*16 -> aligned b128 reads
#define STV  72    // v_sT row stride (d x tokens)
#define STP  72    // p_s row stride (q x key)

__device__ __forceinline__ unsigned short f2bf(float f) {
  union { float f; unsigned u; } cv; cv.f = f;
  unsigned u = cv.u;
  u += 0x7fffu + ((u >> 16) & 1u);   // RNE
  return (unsigned short)(u >> 16);
}

// Pre-pass: w_qkv [96x288], w_proj [96x96] -> bf16 B-fragment blobs.
// Slot layout: blob[(ks*NT + nt)*64 + lane][j] = W[32*ks + (lane>>4)*8 + j][16*nt + (lane&15)]
__global__ void prep_weights(const float* __restrict__ wqkv,
                             const float* __restrict__ wproj,
                             unsigned short* __restrict__ blob) {
  int tid = blockIdx.x * 256 + threadIdx.x;
  if (tid < 3456) {                       // 3 ks * 18 nt * 64 lanes
    int ks = tid / (18 * 64);
    int rem = tid % (18 * 64);
    int nt = rem / 64;
    int lane = rem % 64;
    int k0 = 32 * ks + (lane >> 4) * 8;
    int n  = 16 * nt + (lane & 15);
    unsigned short* dst = blob + tid * 8;
#pragma unroll
    for (int j = 0; j < 8; ++j) dst[j] = f2bf(wqkv[(k0 + j) * 288 + n]);
  } else if (tid < 4608) {                // 3 ks * 6 nt * 64 lanes
    int t = tid - 3456;
    int ks = t / (6 * 64);
    int rem = t % (6 * 64);
    int nt = rem / 64;
    int lane = rem % 64;
    int k0 = 32 * ks + (lane >> 4) * 8;
    int n  = 16 * nt + (lane & 15);
    unsigned short* dst = blob + 3456 * 8 + t * 8;
#pragma unroll
    for (int j = 0; j < 8; ++j) dst[j] = f2bf(wproj[(k0 + j) * 96 + n]);
  }
}

// One block (4 waves) per 7x7 window. Wave w owns token M-tile w (tokens 16w..16w+15, padded to 64).
__global__ __launch_bounds__(256, 3)
void swin_kernel(const float* __restrict__ x,
                 const float* __restrict__ bqkv,
                 const float* __restrict__ bproj,
                 const unsigned short* __restrict__ blob,
                 float* __restrict__ out) {
  __shared__ __align__(16) unsigned short q_s[64 * STQ];   // q [token][d]; later aliased as att
  __shared__ __align__(16) unsigned short k_s[64 * STQ];   // k [token][d]
  __shared__ __align__(16) unsigned short v_sT[96 * STV];  // v [d][token]
  __shared__ __align__(16) unsigned short p_s[64 * STP];   // P [q][key]

  const int tid  = threadIdx.x;
  const int lane = tid & 63;
  const int wv   = tid >> 6;      // wave id == M-tile
  const int l15  = lane & 15;
  const int quad = lane >> 4;

  const int wid = blockIdx.x;
  const int b   = wid >> 10;      // / (32*32)
  const int rem = wid & 1023;
  const int wr  = rem >> 5;
  const int wc  = rem & 31;

  const float4v ZERO4 = {0.f, 0.f, 0.f, 0.f};
  const int trow = 16 * wv + quad * 4;   // C-layout row base (token) for this lane

  // ---------------- Phase 1: QKV = x_win @ w_qkv + b ----------------
  // A-frag: lane holds x[token = 16*wv + l15][ch = 32*ks + quad*8 + j]
  short8 afr[3];
  {
    int ta = 16 * wv + l15;
    if (ta < NTOK) {
      int r = ta / 7, c = ta - 7 * r;
      int gh = wr * 7 + r + 3; if (gh >= IMG) gh -= IMG;
      int gw = wc * 7 + c + 3; if (gw >= IMG) gw -= IMG;
      const float* xp = x + ((b * IMG + gh) * IMG + gw) * CDIM + quad * 8;
#pragma unroll
      for (int ks = 0; ks < 3; ++ks) {
        float4v v0 = *(const float4v*)(xp + 32 * ks);
        float4v v1 = *(const float4v*)(xp + 32 * ks + 4);
        short8 a;
        a[0] = (short)f2bf(v0[0]); a[1] = (short)f2bf(v0[1]);
        a[2] = (short)f2bf(v0[2]); a[3] = (short)f2bf(v0[3]);
        a[4] = (short)f2bf(v1[0]); a[5] = (short)f2bf(v1[1]);
        a[6] = (short)f2bf(v1[2]); a[7] = (short)f2bf(v1[3]);
        afr[ks] = a;
      }
    } else {
      short8 z = {0, 0, 0, 0, 0, 0, 0, 0};
      afr[0] = z; afr[1] = z; afr[2] = z;
    }
  }

  const short8* bq = (const short8*)blob;
#pragma unroll
  for (int nt = 0; nt < 18; ++nt) {
    float4v acc = ZERO4;
#pragma unroll
    for (int ks = 0; ks < 3; ++ks) {
      short8 bf = bq[(ks * 18 + nt) * 64 + lane];
      acc = __builtin_amdgcn_mfma_f32_16x16x32_bf16(afr[ks], bf, acc, 0, 0, 0);
    }
    int col = 16 * nt + l15;
    float bias = bqkv[col];
    if (nt < 6) {                        // q -> q_s[token][d]
#pragma unroll
      for (int r = 0; r < 4; ++r)
        q_s[(trow + r) * STQ + col] = f2bf(acc[r] + bias);
    } else if (nt < 12) {                // k -> k_s[token][d]
#pragma unroll
      for (int r = 0; r < 4; ++r)
        k_s[(trow + r) * STQ + (col - 96)] = f2bf(acc[r] + bias);
    } else {                             // v -> v_sT[d][token], 4 consecutive tokens -> b64
      short4v pk;
#pragma unroll
      for (int r = 0; r < 4; ++r) pk[r] = (short)f2bf(acc[r] + bias);
      *(short4v*)&v_sT[(col - 192) * STV + trow] = pk;
    }
  }
  __syncthreads();   // the only barrier

  // ---------------- Phase 2: attention per head ----------------
  const float cexp = 0.25500526034059f;  // (1/sqrt(32)) * log2(e)
#pragma unroll
  for (int h = 0; h < 3; ++h) {
    // S = q k^T   (M=64 q-tokens: this wave's tile; N=64 keys; K=32)
    short8 qa = *(const short8*)&q_s[(16 * wv + l15) * STQ + 32 * h + quad * 8];
    float4v s[4];
#pragma unroll
    for (int nt = 0; nt < 4; ++nt) {
      short8 kb = *(const short8*)&k_s[(16 * nt + l15) * STQ + 32 * h + quad * 8];
      s[nt] = __builtin_amdgcn_mfma_f32_16x16x32_bf16(qa, kb, ZERO4, 0, 0, 0);
    }
    // masked softmax over 64 keys (4 tiles x 16 lanes), per q-row = (quad,reg)
    float rsi[4];
#pragma unroll
    for (int r = 0; r < 4; ++r) {
      float m0 = -3.0e38f;
#pragma unroll
      for (int nt = 0; nt < 4; ++nt) {
        float sv = (16 * nt + l15 < NTOK) ? s[nt][r] : -3.0e38f;
        s[nt][r] = sv;
        m0 = fmaxf(m0, sv);
      }
      m0 = fmaxf(m0, __shfl_xor(m0, 1, 64));
      m0 = fmaxf(m0, __shfl_xor(m0, 2, 64));
      m0 = fmaxf(m0, __shfl_xor(m0, 4, 64));
      m0 = fmaxf(m0, __shfl_xor(m0, 8, 64));
      float sum = 0.f;
#pragma unroll
      for (int nt = 0; nt < 4; ++nt) {
        float p = exp2f((s[nt][r] - m0) * cexp);   // masked -> exp2(-huge) = 0
        s[nt][r] = p;
        sum += p;
      }
      sum += __shfl_xor(sum, 1, 64);
      sum += __shfl_xor(sum, 2, 64);
      sum += __shfl_xor(sum, 4, 64);
      sum += __shfl_xor(sum, 8, 64);
      rsi[r] = 1.0f / sum;
    }
    // P (C-layout) -> p_s[q][key]  (own rows only; no barrier needed)
#pragma unroll
    for (int nt = 0; nt < 4; ++nt) {
      int key = 16 * nt + l15;
#pragma unroll
      for (int r = 0; r < 4; ++r)
        p_s[(trow + r) * STP + key] = f2bf(s[nt][r]);
    }
    // O = P v   (K = 64 keys -> 2 steps; N = 32 d -> 2 tiles)
    float4v o0 = ZERO4, o1 = ZERO4;
#pragma unroll
    for (int ks = 0; ks < 2; ++ks) {
      short8 pa = *(const short8*)&p_s[(16 * wv + l15) * STP + 32 * ks + quad * 8];
      short8 vb0 = *(const short8*)&v_sT[(32 * h + l15) * STV + 32 * ks + quad * 8];
      short8 vb1 = *(const short8*)&v_sT[(32 * h + 16 + l15) * STV + 32 * ks + quad * 8];
      o0 = __builtin_amdgcn_mfma_f32_16x16x32_bf16(pa, vb0, o0, 0, 0, 0);
      o1 = __builtin_amdgcn_mfma_f32_16x16x32_bf16(pa, vb1, o1, 0, 0, 0);
    }
    // att head h -> q_s cols [32h, 32h+32)  (q cols for head h no longer needed; own rows only)
#pragma unroll
    for (int r = 0; r < 4; ++r) {
      q_s[(trow + r) * STQ + 32 * h + l15]      = f2bf(o0[r] * rsi[r]);
      q_s[(trow + r) * STQ + 32 * h + 16 + l15] = f2bf(o1[r] * rsi[r]);
    }
  }

  // ---------------- Phase 3: proj = att @ w_proj + b ----------------
  const short8* bp = (const short8*)(blob + 3456 * 8);
  float4v pacc[6];
#pragma unroll
  for (int i = 0; i < 6; ++i) pacc[i] = ZERO4;
#pragma unroll
  for (int ks = 0; ks < 3; ++ks) {
    short8 aa = *(const short8*)&q_s[(16 * wv + l15) * STQ + 32 * ks + quad * 8];
#pragma unroll
    for (int nt = 0; nt < 6; ++nt) {
      short8 bf = bp[(ks * 6 + nt) * 64 + lane];
      pacc[nt] = __builtin_amdgcn_mfma_f32_16x16x32_bf16(aa, bf, pacc[nt], 0, 0, 0);
    }
  }
#pragma unroll
  for (int r = 0; r < 4; ++r) {
    int t = trow + r;
    if (t < NTOK) {
      int rr = t / 7, cc = t - 7 * rr;
      int gh = wr * 7 + rr + 3; if (gh >= IMG) gh -= IMG;
      int gw = wc * 7 + cc + 3; if (gw >= IMG) gw -= IMG;
      float* op = out + ((b * IMG + gh) * IMG + gw) * CDIM;
#pragma unroll
      for (int nt = 0; nt < 6; ++nt)
        op[16 * nt + l15] = pacc[nt][r] + bproj[16 * nt + l15];
    }
  }
}

extern "C" void kernel_launch(void* const* d_in, const int* in_sizes, int n_in,
                              void* d_out, int out_size, void* d_ws, size_t ws_size,
                              hipStream_t stream) {
  const float* x      = (const float*)d_in[0];
  const float* w_qkv  = (const float*)d_in[1];
  const float* b_qkv  = (const float*)d_in[2];
  const float* w_proj = (const float*)d_in[3];
  const float* b_proj = (const float*)d_in[4];
  float* out = (float*)d_out;
  unsigned short* blob = (unsigned short*)d_ws;  // 73728 B used

  hipLaunchKernelGGL(prep_weights, dim3(18), dim3(256), 0, stream, w_qkv, w_proj, blob);
  hipLaunchKernelGGL(swin_kernel, dim3(16384), dim3(256), 0, stream,
                     x, b_qkv, b_proj, blob, out);
}